// Round 1
// baseline (92112.750 us; speedup 1.0000x reference)
//
#include <hip/hip_runtime.h>
#include <math.h>

#define B 32
#define S 512
#define T 128
#define V 32000
#define H 512
#define NCHUNK 63   // ceil(32000/512)

__device__ __forceinline__ float dot4(float acc, float4 a, float4 b){
    return fmaf(a.x,b.x, fmaf(a.y,b.y, fmaf(a.z,b.z, fmaf(a.w,b.w, acc))));
}
__device__ __forceinline__ float sigmoidf_(float x){ return 1.0f/(1.0f+expf(-x)); }

// ---------------- encoder step: both directions in one launch ----------------
// block = 256 threads = 32 b (lanes) x 8 j ; grid = (64, 2)
__global__ __launch_bounds__(256) void enc_step_kernel(
    int t,
    const int* __restrict__ input_seq, const float* __restrict__ emb,
    const float* __restrict__ fWih, const float* __restrict__ fWhh,
    const float* __restrict__ fbih, const float* __restrict__ fbhh,
    const float* __restrict__ bWih, const float* __restrict__ bWhh,
    const float* __restrict__ bbih, const float* __restrict__ bbhh,
    float* __restrict__ enc_out, float* __restrict__ out_b)
{
    const int dir = blockIdx.y;
    const int b   = threadIdx.x & 31;
    const int jj  = threadIdx.x >> 5;
    const int j   = blockIdx.x * 8 + jj;

    const float *Wih, *Whh, *bih, *bhh;
    int pos, hpos; float* outp;
    if (dir == 0){ Wih=fWih; Whh=fWhh; bih=fbih; bhh=fbhh; pos=t;     hpos=t-1; outp=enc_out; }
    else         { Wih=bWih; Whh=bWhh; bih=bbih; bhh=bbhh; pos=S-1-t; hpos=S-t; outp=out_b;  }

    const int tok = input_seq[b*S + pos];
    const float4* x4 = (const float4*)(emb + (size_t)tok * H);
    const float* hrow = (t==0) ? nullptr : (outp + ((size_t)b*S + hpos)*H);

    const float4* wir = (const float4*)(Wih + (size_t)(j      )*H);
    const float4* wiz = (const float4*)(Wih + (size_t)(j +   H)*H);
    const float4* win = (const float4*)(Wih + (size_t)(j + 2*H)*H);
    const float4* whr = (const float4*)(Whh + (size_t)(j      )*H);
    const float4* whz = (const float4*)(Whh + (size_t)(j +   H)*H);
    const float4* whn = (const float4*)(Whh + (size_t)(j + 2*H)*H);

    float ir=0.f, iz=0.f, in_=0.f, hr=0.f, hz=0.f, hn=0.f;
    if (hrow){
        const float4* h4 = (const float4*)hrow;
        #pragma unroll 4
        for (int k=0;k<H/4;k++){
            const float4 xv = x4[k], hv = h4[k];
            ir  = dot4(ir , xv, wir[k]);
            iz  = dot4(iz , xv, wiz[k]);
            in_ = dot4(in_, xv, win[k]);
            hr  = dot4(hr , hv, whr[k]);
            hz  = dot4(hz , hv, whz[k]);
            hn  = dot4(hn , hv, whn[k]);
        }
    } else {
        #pragma unroll 4
        for (int k=0;k<H/4;k++){
            const float4 xv = x4[k];
            ir  = dot4(ir , xv, wir[k]);
            iz  = dot4(iz , xv, wiz[k]);
            in_ = dot4(in_, xv, win[k]);
        }
    }
    const float r = sigmoidf_(ir + bih[j]     + hr + bhh[j]);
    const float z = sigmoidf_(iz + bih[H+j]   + hz + bhh[H+j]);
    const float n = tanhf(in_ + bih[2*H+j] + r*(hn + bhh[2*H+j]));
    const float hprev = hrow ? hrow[j] : 0.0f;
    outp[((size_t)b*S + pos)*H + j] = (1.0f - z)*n + z*hprev;
}

// ---------------- prep: h_dec0 = hf_last + hb_last ; tok=SOS ; loss=0 -------
__global__ void prep_kernel(const float* __restrict__ enc_out, const float* __restrict__ out_b,
                            float* __restrict__ hdec0, int* __restrict__ tok, float* __restrict__ lossb)
{
    const int gid = blockIdx.x*256 + threadIdx.x;   // 16384 = B*H
    const int b = gid >> 9, j = gid & 511;
    hdec0[gid] = enc_out[((size_t)b*S + (S-1))*H + j] + out_b[((size_t)b*S)*H + j];
    if (gid < B){ tok[gid] = 1; lossb[gid] = 0.0f; }
}

// ---------------- combine: enc_out += out_b ---------------------------------
__global__ void combine_kernel(float* __restrict__ enc_out, const float* __restrict__ out_b)
{
    const size_t i = (size_t)blockIdx.x*256 + threadIdx.x;   // over float4, 2,097,152
    float4* a = (float4*)enc_out; const float4* c = (const float4*)out_b;
    float4 x = a[i]; const float4 y = c[i];
    x.x += y.x; x.y += y.y; x.z += y.z; x.w += y.w;
    a[i] = x;
}

// ---------------- decoder GRU step ------------------------------------------
__global__ __launch_bounds__(256) void dec_gru_kernel(
    const int* __restrict__ tok, const float* __restrict__ emb,
    const float* __restrict__ Wih, const float* __restrict__ Whh,
    const float* __restrict__ bih, const float* __restrict__ bhh,
    const float* __restrict__ h_in, float* __restrict__ h_out)
{
    const int b  = threadIdx.x & 31;
    const int jj = threadIdx.x >> 5;
    const int j  = blockIdx.x * 8 + jj;

    const float4* x4 = (const float4*)(emb + (size_t)tok[b] * H);
    const float4* h4 = (const float4*)(h_in + (size_t)b*H);

    const float4* wir = (const float4*)(Wih + (size_t)(j      )*H);
    const float4* wiz = (const float4*)(Wih + (size_t)(j +   H)*H);
    const float4* win = (const float4*)(Wih + (size_t)(j + 2*H)*H);
    const float4* whr = (const float4*)(Whh + (size_t)(j      )*H);
    const float4* whz = (const float4*)(Whh + (size_t)(j +   H)*H);
    const float4* whn = (const float4*)(Whh + (size_t)(j + 2*H)*H);

    float ir=0.f, iz=0.f, in_=0.f, hr=0.f, hz=0.f, hn=0.f;
    #pragma unroll 4
    for (int k=0;k<H/4;k++){
        const float4 xv = x4[k], hv = h4[k];
        ir  = dot4(ir , xv, wir[k]);
        iz  = dot4(iz , xv, wiz[k]);
        in_ = dot4(in_, xv, win[k]);
        hr  = dot4(hr , hv, whr[k]);
        hz  = dot4(hz , hv, whz[k]);
        hn  = dot4(hn , hv, whn[k]);
    }
    const float r = sigmoidf_(ir + bih[j]     + hr + bhh[j]);
    const float z = sigmoidf_(iz + bih[H+j]   + hz + bhh[H+j]);
    const float n = tanhf(in_ + bih[2*H+j] + r*(hn + bhh[2*H+j]));
    const float hprev = h_in[(size_t)b*H + j];
    h_out[(size_t)b*H + j] = (1.0f - z)*n + z*hprev;
}

// ---------------- attention: one block per batch row ------------------------
__global__ __launch_bounds__(256) void attn_kernel(
    const float* __restrict__ hn, const float* __restrict__ enc,
    const float* __restrict__ attW, const float* __restrict__ attb,
    float* __restrict__ att_out)
{
    __shared__ float sh_hn[H];
    __shared__ float sh_w[S];
    __shared__ float sh_cat[2*H];
    __shared__ float red[256];
    const int b = blockIdx.x, tid = threadIdx.x;
    const float* E = enc + (size_t)b*S*H;

    for (int i=tid;i<H;i+=256){ float v = hn[(size_t)b*H+i]; sh_hn[i]=v; sh_cat[H+i]=v; }
    __syncthreads();

    // scores
    {
        const float4* h4 = (const float4*)sh_hn;
        const float4* e0 = (const float4*)(E + (size_t)tid*H);
        const float4* e1 = (const float4*)(E + (size_t)(tid+256)*H);
        float a0=0.f, a1=0.f;
        #pragma unroll 4
        for (int k=0;k<H/4;k++){ const float4 hv=h4[k]; a0=dot4(a0,hv,e0[k]); a1=dot4(a1,hv,e1[k]); }
        sh_w[tid]=a0; sh_w[tid+256]=a1;
    }
    __syncthreads();

    // softmax over S
    float m = fmaxf(sh_w[tid], sh_w[tid+256]);
    red[tid]=m; __syncthreads();
    for (int off=128; off>0; off>>=1){ if (tid<off) red[tid]=fmaxf(red[tid],red[tid+off]); __syncthreads(); }
    m = red[0]; __syncthreads();
    float e0v = expf(sh_w[tid]-m), e1v = expf(sh_w[tid+256]-m);
    sh_w[tid]=e0v; sh_w[tid+256]=e1v;
    red[tid]=e0v+e1v; __syncthreads();
    for (int off=128; off>0; off>>=1){ if (tid<off) red[tid]+=red[tid+off]; __syncthreads(); }
    const float inv = 1.0f/red[0]; __syncthreads();
    sh_w[tid]*=inv; sh_w[tid+256]*=inv;
    __syncthreads();

    // ctx (coalesced over h)
    {
        float a0=0.f, a1=0.f;
        for (int s=0;s<S;s++){
            const float w = sh_w[s];
            const float* row = E + (size_t)s*H;
            a0 = fmaf(w, row[tid],     a0);
            a1 = fmaf(w, row[tid+256], a1);
        }
        sh_cat[tid]=a0; sh_cat[tid+256]=a1;
    }
    __syncthreads();

    // att_out = tanh(cat @ attW.T + attb)
    {
        const float4* c4 = (const float4*)sh_cat;
        #pragma unroll
        for (int hh=0; hh<2; hh++){
            const int h = tid + hh*256;
            const float4* w4 = (const float4*)(attW + (size_t)h*2*H);
            float acc=0.f;
            #pragma unroll 4
            for (int k=0;k<2*H/4;k++) acc = dot4(acc, c4[k], w4[k]);
            att_out[(size_t)b*H + h] = tanhf(acc + attb[h]);
        }
    }
}

// ---------------- logits chunk: per-chunk online-softmax partials -----------
__global__ __launch_bounds__(256) void logits_kernel(
    const float* __restrict__ att_out,
    const float* __restrict__ outW, const float* __restrict__ outBias,
    float* __restrict__ logits, float* __restrict__ pm, float* __restrict__ ps, int* __restrict__ pidx)
{
    __shared__ float sh_a[H];
    __shared__ float redv[256];
    __shared__ int   redi[256];
    const int chunk = blockIdx.x, b = blockIdx.y, tid = threadIdx.x;
    for (int i=tid;i<H;i+=256) sh_a[i]=att_out[(size_t)b*H+i];
    __syncthreads();

    const int c0 = chunk*512 + tid;       // always < V
    const int c1 = c0 + 256;              // may be >= V in last chunk
    const float4* a4 = (const float4*)sh_a;
    float l0, l1 = -INFINITY;
    {
        const float4* w4 = (const float4*)(outW + (size_t)c0*H);
        float acc=0.f;
        #pragma unroll 4
        for (int k=0;k<H/4;k++) acc = dot4(acc, a4[k], w4[k]);
        l0 = acc + outBias[c0];
        logits[(size_t)b*V + c0] = l0;
    }
    if (c1 < V){
        const float4* w4 = (const float4*)(outW + (size_t)c1*H);
        float acc=0.f;
        #pragma unroll 4
        for (int k=0;k<H/4;k++) acc = dot4(acc, a4[k], w4[k]);
        l1 = acc + outBias[c1];
        logits[(size_t)b*V + c1] = l1;
    }
    // block max
    redv[tid] = fmaxf(l0,l1); __syncthreads();
    for (int off=128; off>0; off>>=1){ if (tid<off) redv[tid]=fmaxf(redv[tid],redv[tid+off]); __syncthreads(); }
    const float M = redv[0]; __syncthreads();
    // sum exp
    redv[tid] = expf(l0-M) + expf(l1-M); __syncthreads();
    for (int off=128; off>0; off>>=1){ if (tid<off) redv[tid]+=redv[tid+off]; __syncthreads(); }
    const float Ssum = redv[0]; __syncthreads();
    // argmax (first-max tie-break)
    float bv; int bi;
    if (l1 > l0){ bv=l1; bi=c1; } else { bv=l0; bi=c0; }
    redv[tid]=bv; redi[tid]=bi; __syncthreads();
    for (int off=128; off>0; off>>=1){
        if (tid<off){
            const float ov=redv[tid+off]; const int oi=redi[tid+off];
            if (ov > redv[tid] || (ov == redv[tid] && oi < redi[tid])){ redv[tid]=ov; redi[tid]=oi; }
        }
        __syncthreads();
    }
    if (tid==0){
        pm[b*NCHUNK+chunk]=M; ps[b*NCHUNK+chunk]=Ssum; pidx[b*NCHUNK+chunk]=redi[0];
    }
}

// ---------------- merge: logsumexp + loss + argmax-feedback token -----------
__global__ void merge_kernel(int t, const int* __restrict__ target_seq,
    const float* __restrict__ logits, const float* __restrict__ pm,
    const float* __restrict__ ps, const int* __restrict__ pidx,
    float* __restrict__ lossb, int* __restrict__ tok)
{
    const int b = blockIdx.x, lane = threadIdx.x;   // 64 lanes
    float m = -INFINITY, s = 0.0f; float av = -INFINITY; int ai = 0x7FFFFFFF;
    if (lane < NCHUNK){ m = pm[b*NCHUNK+lane]; s = ps[b*NCHUNK+lane]; ai = pidx[b*NCHUNK+lane]; av = m; }
    float M = m;
    for (int off=32; off>0; off>>=1) M = fmaxf(M, __shfl_down(M, off));
    M = __shfl(M, 0);
    float e = (lane < NCHUNK) ? s*expf(m-M) : 0.0f;
    for (int off=32; off>0; off>>=1) e += __shfl_down(e, off);
    for (int off=32; off>0; off>>=1){
        const float ov = __shfl_down(av, off); const int oi = __shfl_down(ai, off);
        if (ov > av || (ov == av && oi < ai)){ av = ov; ai = oi; }
    }
    if (lane==0){
        const float lse = M + logf(e);
        const int tgt = target_seq[b*T + t];
        lossb[b] += lse - logits[(size_t)b*V + tgt];
        tok[b] = ai;
    }
}

// ---------------- finalize: mean(loss/T) ------------------------------------
__global__ void finalize_kernel(const float* __restrict__ lossb, float* __restrict__ out)
{
    const int lane = threadIdx.x;
    float v = (lane < B) ? lossb[lane] : 0.0f;
    for (int off=32; off>0; off>>=1) v += __shfl_down(v, off);
    if (lane==0) out[0] = v / (float)(B*T);
}

extern "C" void kernel_launch(void* const* d_in, const int* in_sizes, int n_in,
                              void* d_out, int out_size, void* d_ws, size_t ws_size,
                              hipStream_t stream)
{
    const int*   input_seq  = (const int*)  d_in[0];
    const int*   target_seq = (const int*)  d_in[1];
    const float* emb    = (const float*)d_in[2];
    const float* efWih  = (const float*)d_in[3];
    const float* efWhh  = (const float*)d_in[4];
    const float* efbih  = (const float*)d_in[5];
    const float* efbhh  = (const float*)d_in[6];
    const float* ebWih  = (const float*)d_in[7];
    const float* ebWhh  = (const float*)d_in[8];
    const float* ebbih  = (const float*)d_in[9];
    const float* ebbhh  = (const float*)d_in[10];
    const float* dWih   = (const float*)d_in[11];
    const float* dWhh   = (const float*)d_in[12];
    const float* dbih   = (const float*)d_in[13];
    const float* dbhh   = (const float*)d_in[14];
    const float* attW   = (const float*)d_in[15];
    const float* attb   = (const float*)d_in[16];
    const float* outW   = (const float*)d_in[17];
    const float* outBias= (const float*)d_in[18];

    // workspace layout (floats) — total ~71.5 MB
    float* ws      = (float*)d_ws;
    float* enc_out = ws;                                   // B*S*H
    float* outb    = enc_out + (size_t)B*S*H;              // B*S*H
    float* attout  = outb    + (size_t)B*S*H;              // B*H
    float* logits  = attout  + (size_t)B*H;                // B*V
    float* pm      = logits  + (size_t)B*V;                // B*NCHUNK
    float* ps      = pm      + (size_t)B*NCHUNK;           // B*NCHUNK
    int*   pidx    = (int*)(ps + (size_t)B*NCHUNK);        // B*NCHUNK
    float* hdec    = (float*)(pidx + (size_t)B*NCHUNK);    // 2*B*H
    float* lossb   = hdec    + (size_t)2*B*H;              // B
    int*   tok     = (int*)(lossb + B);                    // B

    // ---- encoder: 512 dependent steps, both directions per launch ----
    for (int t=0;t<S;t++){
        enc_step_kernel<<<dim3(64,2), 256, 0, stream>>>(t, input_seq, emb,
            efWih, efWhh, efbih, efbhh, ebWih, ebWhh, ebbih, ebbhh, enc_out, outb);
    }
    prep_kernel<<<64, 256, 0, stream>>>(enc_out, outb, hdec, tok, lossb);
    combine_kernel<<<(B*(size_t)S*H/4)/256, 256, 0, stream>>>(enc_out, outb);

    // ---- decoder: 128 dependent steps ----
    for (int t=0;t<T;t++){
        float* hin  = hdec + (size_t)(t&1)*B*H;
        float* hout = hdec + (size_t)((t+1)&1)*B*H;
        dec_gru_kernel<<<64, 256, 0, stream>>>(tok, emb, dWih, dWhh, dbih, dbhh, hin, hout);
        attn_kernel<<<B, 256, 0, stream>>>(hout, enc_out, attW, attb, attout);
        logits_kernel<<<dim3(NCHUNK,B), 256, 0, stream>>>(attout, outW, outBias, logits, pm, ps, pidx);
        merge_kernel<<<B, 64, 0, stream>>>(t, target_seq, logits, pm, ps, pidx, lossb, tok);
    }
    finalize_kernel<<<1, 64, 0, stream>>>(lossb, (float*)d_out);
}

// Round 2
// 51560.211 us; speedup vs baseline: 1.7865x; 1.7865x over previous
//
#include <hip/hip_runtime.h>
#include <math.h>

#define B 32
#define S 512
#define T 128
#define V 32000
#define H 512
#define LCHUNK 250          // logits chunks: 250 blocks x 128 rows = 32000
#define LDSPITCH 264        // 256 k-floats + 8 pad (2-way bank aliasing = free, 16B aligned)

__device__ __forceinline__ float dot4(float acc, float4 a, float4 b){
    return fmaf(a.x,b.x, fmaf(a.y,b.y, fmaf(a.z,b.z, fmaf(a.w,b.w, acc))));
}
__device__ __forceinline__ float sigmoidf_(float x){ return 1.0f/(1.0f+expf(-x)); }

// ---------------- encoder step: both directions in one launch ----------------
__global__ __launch_bounds__(256) void enc_step_kernel(
    int t,
    const int* __restrict__ input_seq, const float* __restrict__ emb,
    const float* __restrict__ fWih, const float* __restrict__ fWhh,
    const float* __restrict__ fbih, const float* __restrict__ fbhh,
    const float* __restrict__ bWih, const float* __restrict__ bWhh,
    const float* __restrict__ bbih, const float* __restrict__ bbhh,
    float* __restrict__ enc_out, float* __restrict__ out_b)
{
    const int dir = blockIdx.y;
    const int b   = threadIdx.x & 31;
    const int jj  = threadIdx.x >> 5;
    const int j   = blockIdx.x * 8 + jj;

    const float *Wih, *Whh, *bih, *bhh;
    int pos, hpos; float* outp;
    if (dir == 0){ Wih=fWih; Whh=fWhh; bih=fbih; bhh=fbhh; pos=t;     hpos=t-1; outp=enc_out; }
    else         { Wih=bWih; Whh=bWhh; bih=bbih; bhh=bbhh; pos=S-1-t; hpos=S-t; outp=out_b;  }

    const int tok = input_seq[b*S + pos];
    const float4* x4 = (const float4*)(emb + (size_t)tok * H);
    const float* hrow = (t==0) ? nullptr : (outp + ((size_t)b*S + hpos)*H);

    const float4* wir = (const float4*)(Wih + (size_t)(j      )*H);
    const float4* wiz = (const float4*)(Wih + (size_t)(j +   H)*H);
    const float4* win = (const float4*)(Wih + (size_t)(j + 2*H)*H);
    const float4* whr = (const float4*)(Whh + (size_t)(j      )*H);
    const float4* whz = (const float4*)(Whh + (size_t)(j +   H)*H);
    const float4* whn = (const float4*)(Whh + (size_t)(j + 2*H)*H);

    float ir=0.f, iz=0.f, in_=0.f, hr=0.f, hz=0.f, hn=0.f;
    if (hrow){
        const float4* h4 = (const float4*)hrow;
        #pragma unroll 4
        for (int k=0;k<H/4;k++){
            const float4 xv = x4[k], hv = h4[k];
            ir  = dot4(ir , xv, wir[k]);
            iz  = dot4(iz , xv, wiz[k]);
            in_ = dot4(in_, xv, win[k]);
            hr  = dot4(hr , hv, whr[k]);
            hz  = dot4(hz , hv, whz[k]);
            hn  = dot4(hn , hv, whn[k]);
        }
    } else {
        #pragma unroll 4
        for (int k=0;k<H/4;k++){
            const float4 xv = x4[k];
            ir  = dot4(ir , xv, wir[k]);
            iz  = dot4(iz , xv, wiz[k]);
            in_ = dot4(in_, xv, win[k]);
        }
    }
    const float r = sigmoidf_(ir + bih[j]     + hr + bhh[j]);
    const float z = sigmoidf_(iz + bih[H+j]   + hz + bhh[H+j]);
    const float n = tanhf(in_ + bih[2*H+j] + r*(hn + bhh[2*H+j]));
    const float hprev = hrow ? hrow[j] : 0.0f;
    outp[((size_t)b*S + pos)*H + j] = (1.0f - z)*n + z*hprev;
}

// ---------------- prep: h_dec0 = hf_last + hb_last ; tok=SOS ; loss=0 -------
__global__ void prep_kernel(const float* __restrict__ enc_out, const float* __restrict__ out_b,
                            float* __restrict__ hdec0, int* __restrict__ tok, float* __restrict__ lossb)
{
    const int gid = blockIdx.x*256 + threadIdx.x;   // 16384 = B*H
    const int b = gid >> 9, j = gid & 511;
    hdec0[gid] = enc_out[((size_t)b*S + (S-1))*H + j] + out_b[((size_t)b*S)*H + j];
    if (gid < B){ tok[gid] = 1; lossb[gid] = 0.0f; }
}

// ---------------- combine: enc_out += out_b ---------------------------------
__global__ void combine_kernel(float* __restrict__ enc_out, const float* __restrict__ out_b)
{
    const size_t i = (size_t)blockIdx.x*256 + threadIdx.x;
    float4* a = (float4*)enc_out; const float4* c = (const float4*)out_b;
    float4 x = a[i]; const float4 y = c[i];
    x.x += y.x; x.y += y.y; x.z += y.z; x.w += y.w;
    a[i] = x;
}

// ---------------- decoder GRU step (also writes hn into cat[:,H:]) ----------
__global__ __launch_bounds__(256) void dec_gru_kernel(
    const int* __restrict__ tok, const float* __restrict__ emb,
    const float* __restrict__ Wih, const float* __restrict__ Whh,
    const float* __restrict__ bih, const float* __restrict__ bhh,
    const float* __restrict__ h_in, float* __restrict__ h_out, float* __restrict__ cat)
{
    const int b  = threadIdx.x & 31;
    const int jj = threadIdx.x >> 5;
    const int j  = blockIdx.x * 8 + jj;

    const float4* x4 = (const float4*)(emb + (size_t)tok[b] * H);
    const float4* h4 = (const float4*)(h_in + (size_t)b*H);

    const float4* wir = (const float4*)(Wih + (size_t)(j      )*H);
    const float4* wiz = (const float4*)(Wih + (size_t)(j +   H)*H);
    const float4* win = (const float4*)(Wih + (size_t)(j + 2*H)*H);
    const float4* whr = (const float4*)(Whh + (size_t)(j      )*H);
    const float4* whz = (const float4*)(Whh + (size_t)(j +   H)*H);
    const float4* whn = (const float4*)(Whh + (size_t)(j + 2*H)*H);

    float ir=0.f, iz=0.f, in_=0.f, hr=0.f, hz=0.f, hn=0.f;
    #pragma unroll 4
    for (int k=0;k<H/4;k++){
        const float4 xv = x4[k], hv = h4[k];
        ir  = dot4(ir , xv, wir[k]);
        iz  = dot4(iz , xv, wiz[k]);
        in_ = dot4(in_, xv, win[k]);
        hr  = dot4(hr , hv, whr[k]);
        hz  = dot4(hz , hv, whz[k]);
        hn  = dot4(hn , hv, whn[k]);
    }
    const float r = sigmoidf_(ir + bih[j]     + hr + bhh[j]);
    const float z = sigmoidf_(iz + bih[H+j]   + hz + bhh[H+j]);
    const float n = tanhf(in_ + bih[2*H+j] + r*(hn + bhh[2*H+j]));
    const float hprev = h_in[(size_t)b*H + j];
    const float hv = (1.0f - z)*n + z*hprev;
    h_out[(size_t)b*H + j] = hv;
    cat[(size_t)b*(2*H) + H + j] = hv;
}

// ---------------- scores: grid (B, 8), 64 s-rows per block ------------------
__global__ __launch_bounds__(256) void scores_kernel(
    const float* __restrict__ hn, const float* __restrict__ enc, float* __restrict__ scores)
{
    __shared__ float sh_hn[H];
    const int b = blockIdx.x, sc = blockIdx.y, tid = threadIdx.x;
    sh_hn[tid]     = hn[(size_t)b*H + tid];
    sh_hn[tid+256] = hn[(size_t)b*H + tid + 256];
    __syncthreads();
    const int sl = tid >> 2, q = tid & 3;
    const int s = sc*64 + sl;
    const float4* e4 = (const float4*)(enc + ((size_t)b*S + s)*H + q*128);
    const float4* h4 = (const float4*)(sh_hn + q*128);
    float a = 0.f;
    #pragma unroll 8
    for (int k=0;k<32;k++) a = dot4(a, h4[k], e4[k]);
    a += __shfl_xor(a, 1);
    a += __shfl_xor(a, 2);
    if (q == 0) scores[b*S + s] = a;
}

// ---------------- ctx: grid (B, 4); local softmax + weighted sum ------------
__global__ __launch_bounds__(256) void ctx_kernel(
    const float* __restrict__ scores, const float* __restrict__ enc, float* __restrict__ cat)
{
    __shared__ float sh_w[S];
    __shared__ float red[256];
    __shared__ float part[256];
    const int b = blockIdx.x, hc = blockIdx.y, tid = threadIdx.x;

    const float s0 = scores[b*S + tid], s1 = scores[b*S + tid + 256];
    red[tid] = fmaxf(s0, s1); __syncthreads();
    for (int off=128; off>0; off>>=1){ if (tid<off) red[tid]=fmaxf(red[tid],red[tid+off]); __syncthreads(); }
    const float M = red[0]; __syncthreads();
    const float e0 = expf(s0-M), e1 = expf(s1-M);
    red[tid] = e0+e1; __syncthreads();
    for (int off=128; off>0; off>>=1){ if (tid<off) red[tid]+=red[tid+off]; __syncthreads(); }
    const float inv = 1.0f/red[0];
    sh_w[tid] = e0*inv; sh_w[tid+256] = e1*inv;
    __syncthreads();

    const int col = hc*128 + (tid & 127);
    const int sg  = tid >> 7;
    const float* Ec = enc + (size_t)b*S*H + col;
    float acc = 0.f;
    #pragma unroll 8
    for (int s=sg; s<S; s+=2) acc = fmaf(sh_w[s], Ec[(size_t)s*H], acc);
    part[tid] = acc; __syncthreads();
    if (tid < 128) cat[(size_t)b*(2*H) + hc*128 + tid] = part[tid] + part[tid+128];
}

// ---------------- proj: att_out = tanh(cat @ attW.T + attb) -----------------
// grid 32 blocks x (16 h' rows, all 32 b); attW read exactly once per step.
__global__ __launch_bounds__(256) void proj_kernel(
    const float* __restrict__ cat, const float* __restrict__ attW,
    const float* __restrict__ attb, float* __restrict__ att_out)
{
    __shared__ float sh[32*LDSPITCH];
    const int blk = blockIdx.x, tid = threadIdx.x;
    const int hl = tid & 15;            // 16 h' rows
    const int bp = tid >> 4;            // 16 groups x 2 b
    const int b0 = bp*2, b1 = b0+1;
    const int row = blk*16 + hl;
    const float4* w4 = (const float4*)(attW + (size_t)row*(2*H));
    float4* sh4 = (float4*)sh;
    float acc0 = 0.f, acc1 = 0.f;

    for (int p=0; p<4; p++){
        // stage cat[:, p*256 : (p+1)*256] -> sh (32 x 264 pitch)
        #pragma unroll
        for (int ii=0; ii<8; ii++){
            const int f4 = tid + 256*ii;         // 0..2047
            const int bb = f4 >> 6, k4 = f4 & 63;
            sh4[bb*(LDSPITCH/4) + k4] = ((const float4*)cat)[(size_t)bb*(2*H/4) + p*64 + k4];
        }
        __syncthreads();
        #pragma unroll 8
        for (int k=0;k<64;k++){
            const float4 wv = w4[p*64 + k];
            const float4 a0 = sh4[b0*(LDSPITCH/4) + k];
            const float4 a1 = sh4[b1*(LDSPITCH/4) + k];
            acc0 = dot4(acc0, wv, a0);
            acc1 = dot4(acc1, wv, a1);
        }
        __syncthreads();
    }
    const float bias = attb[row];
    att_out[(size_t)b0*H + row] = tanhf(acc0 + bias);
    att_out[(size_t)b1*H + row] = tanhf(acc1 + bias);
}

// ---------------- logits: grid 250 blocks x (128 rows, all 32 b) ------------
// outW read exactly once per step; online-softmax partials per (b, chunk).
__global__ __launch_bounds__(256) void logits_kernel(
    const float* __restrict__ att_out,
    const float* __restrict__ outW, const float* __restrict__ outBias,
    float* __restrict__ pm, float* __restrict__ ps, int* __restrict__ pidx)
{
    __shared__ float sh[32*LDSPITCH];
    const int blk = blockIdx.x, tid = threadIdx.x;
    const int rg = tid & 31;            // 32 row-groups
    const int bg = tid >> 5;            // 8 batch-groups x 4 b
    const int r0 = blk*128 + rg;        // rows r0, r0+32, r0+64, r0+96
    const float4* w0 = (const float4*)(outW + (size_t)(r0     )*H);
    const float4* w1 = (const float4*)(outW + (size_t)(r0 + 32)*H);
    const float4* w2 = (const float4*)(outW + (size_t)(r0 + 64)*H);
    const float4* w3 = (const float4*)(outW + (size_t)(r0 + 96)*H);
    float4* sh4 = (float4*)sh;
    float acc[4][4];
    #pragma unroll
    for (int i=0;i<4;i++){ acc[i][0]=0.f; acc[i][1]=0.f; acc[i][2]=0.f; acc[i][3]=0.f; }

    for (int ph=0; ph<2; ph++){
        #pragma unroll
        for (int ii=0; ii<8; ii++){
            const int f4 = tid + 256*ii;
            const int bb = f4 >> 6, k4 = f4 & 63;
            sh4[bb*(LDSPITCH/4) + k4] = ((const float4*)att_out)[(size_t)bb*(H/4) + ph*64 + k4];
        }
        __syncthreads();
        #pragma unroll 4
        for (int k=0;k<64;k++){
            const float4 a0 = sh4[(bg*4+0)*(LDSPITCH/4) + k];
            const float4 a1 = sh4[(bg*4+1)*(LDSPITCH/4) + k];
            const float4 a2 = sh4[(bg*4+2)*(LDSPITCH/4) + k];
            const float4 a3 = sh4[(bg*4+3)*(LDSPITCH/4) + k];
            const int kk = ph*64 + k;
            {   const float4 wv = w0[kk];
                acc[0][0]=dot4(acc[0][0],wv,a0); acc[0][1]=dot4(acc[0][1],wv,a1);
                acc[0][2]=dot4(acc[0][2],wv,a2); acc[0][3]=dot4(acc[0][3],wv,a3); }
            {   const float4 wv = w1[kk];
                acc[1][0]=dot4(acc[1][0],wv,a0); acc[1][1]=dot4(acc[1][1],wv,a1);
                acc[1][2]=dot4(acc[1][2],wv,a2); acc[1][3]=dot4(acc[1][3],wv,a3); }
            {   const float4 wv = w2[kk];
                acc[2][0]=dot4(acc[2][0],wv,a0); acc[2][1]=dot4(acc[2][1],wv,a1);
                acc[2][2]=dot4(acc[2][2],wv,a2); acc[2][3]=dot4(acc[2][3],wv,a3); }
            {   const float4 wv = w3[kk];
                acc[3][0]=dot4(acc[3][0],wv,a0); acc[3][1]=dot4(acc[3][1],wv,a1);
                acc[3][2]=dot4(acc[3][2],wv,a2); acc[3][3]=dot4(acc[3][3],wv,a3); }
        }
        __syncthreads();
    }

    const float bias0 = outBias[r0], bias1 = outBias[r0+32], bias2 = outBias[r0+64], bias3 = outBias[r0+96];
    #pragma unroll
    for (int j=0;j<4;j++){
        float l0 = acc[0][j]+bias0, l1 = acc[1][j]+bias1, l2 = acc[2][j]+bias2, l3 = acc[3][j]+bias3;
        float M = fmaxf(fmaxf(l0,l1), fmaxf(l2,l3));
        #pragma unroll
        for (int m=1;m<32;m<<=1) M = fmaxf(M, __shfl_xor(M, m));
        float sum = expf(l0-M)+expf(l1-M)+expf(l2-M)+expf(l3-M);
        #pragma unroll
        for (int m=1;m<32;m<<=1) sum += __shfl_xor(sum, m);
        float bv = l0; int bi = r0;
        if (l1 > bv){ bv=l1; bi=r0+32; }
        if (l2 > bv){ bv=l2; bi=r0+64; }
        if (l3 > bv){ bv=l3; bi=r0+96; }
        #pragma unroll
        for (int m=1;m<32;m<<=1){
            const float ov = __shfl_xor(bv, m); const int oi = __shfl_xor(bi, m);
            if (ov > bv || (ov == bv && oi < bi)){ bv=ov; bi=oi; }
        }
        if (rg == 0){
            const int b = bg*4 + j;
            pm[b*LCHUNK + blk] = M;
            ps[b*LCHUNK + blk] = sum;
            pidx[b*LCHUNK + blk] = bi;
        }
    }
}

// ---------------- merge: logsumexp + target logit + loss + next token -------
__global__ __launch_bounds__(256) void merge_kernel(
    int t, const int* __restrict__ target_seq,
    const float* __restrict__ att_out, const float* __restrict__ outW, const float* __restrict__ outBias,
    const float* __restrict__ pm, const float* __restrict__ ps, const int* __restrict__ pidx,
    float* __restrict__ lossb, int* __restrict__ tok)
{
    __shared__ float ra[256];
    __shared__ float rb[256];
    __shared__ int   ric[256];
    const int b = blockIdx.x, tid = threadIdx.x;
    const int tgt = target_seq[b*T + t];

    // target logit dot
    float d = att_out[(size_t)b*H + tid]       * outW[(size_t)tgt*H + tid]
            + att_out[(size_t)b*H + tid + 256] * outW[(size_t)tgt*H + tid + 256];

    const bool valid = (tid < LCHUNK);
    const float m  = valid ? pm[b*LCHUNK + tid] : -INFINITY;
    const float sv = valid ? ps[b*LCHUNK + tid] : 0.0f;
    const int   iv = valid ? pidx[b*LCHUNK + tid] : 0x7FFFFFFF;

    // global max
    ra[tid] = m; __syncthreads();
    for (int off=128; off>0; off>>=1){ if (tid<off) ra[tid]=fmaxf(ra[tid],ra[tid+off]); __syncthreads(); }
    const float M = ra[0]; __syncthreads();
    // sum of exp
    ra[tid] = valid ? sv*expf(m-M) : 0.0f; __syncthreads();
    for (int off=128; off>0; off>>=1){ if (tid<off) ra[tid]+=ra[tid+off]; __syncthreads(); }
    const float SE = ra[0]; __syncthreads();
    // argmax across chunks
    rb[tid] = m; ric[tid] = iv; __syncthreads();
    for (int off=128; off>0; off>>=1){
        if (tid<off){
            const float ov = rb[tid+off]; const int oi = ric[tid+off];
            if (ov > rb[tid] || (ov == rb[tid] && oi < ric[tid])){ rb[tid]=ov; ric[tid]=oi; }
        }
        __syncthreads();
    }
    const int amax = ric[0]; __syncthreads();
    // target dot reduce
    ra[tid] = d; __syncthreads();
    for (int off=128; off>0; off>>=1){ if (tid<off) ra[tid]+=ra[tid+off]; __syncthreads(); }

    if (tid == 0){
        const float lse = M + logf(SE);
        lossb[b] += lse - (ra[0] + outBias[tgt]);
        tok[b] = amax;
    }
}

// ---------------- finalize: mean(loss/T) ------------------------------------
__global__ void finalize_kernel(const float* __restrict__ lossb, float* __restrict__ out)
{
    const int lane = threadIdx.x;
    float v = (lane < B) ? lossb[lane] : 0.0f;
    for (int off=32; off>0; off>>=1) v += __shfl_down(v, off);
    if (lane==0) out[0] = v / (float)(B*T);
}

extern "C" void kernel_launch(void* const* d_in, const int* in_sizes, int n_in,
                              void* d_out, int out_size, void* d_ws, size_t ws_size,
                              hipStream_t stream)
{
    const int*   input_seq  = (const int*)  d_in[0];
    const int*   target_seq = (const int*)  d_in[1];
    const float* emb    = (const float*)d_in[2];
    const float* efWih  = (const float*)d_in[3];
    const float* efWhh  = (const float*)d_in[4];
    const float* efbih  = (const float*)d_in[5];
    const float* efbhh  = (const float*)d_in[6];
    const float* ebWih  = (const float*)d_in[7];
    const float* ebWhh  = (const float*)d_in[8];
    const float* ebbih  = (const float*)d_in[9];
    const float* ebbhh  = (const float*)d_in[10];
    const float* dWih   = (const float*)d_in[11];
    const float* dWhh   = (const float*)d_in[12];
    const float* dbih   = (const float*)d_in[13];
    const float* dbhh   = (const float*)d_in[14];
    const float* attW   = (const float*)d_in[15];
    const float* attb   = (const float*)d_in[16];
    const float* outW   = (const float*)d_in[17];
    const float* outBias= (const float*)d_in[18];

    // workspace layout (floats) — ~67.6 MB
    float* ws      = (float*)d_ws;
    float* enc_out = ws;                                    // B*S*H
    float* outb    = enc_out + (size_t)B*S*H;               // B*S*H
    float* cat     = outb    + (size_t)B*S*H;               // B*2H
    float* attout  = cat     + (size_t)B*2*H;               // B*H
    float* scores  = attout  + (size_t)B*H;                 // B*S
    float* pm      = scores  + (size_t)B*S;                 // B*LCHUNK
    float* ps      = pm      + (size_t)B*LCHUNK;            // B*LCHUNK
    int*   pidx    = (int*)(ps + (size_t)B*LCHUNK);         // B*LCHUNK
    float* hdec    = (float*)(pidx + (size_t)B*LCHUNK);     // 2*B*H
    float* lossb   = hdec    + (size_t)2*B*H;               // B
    int*   tok     = (int*)(lossb + B);                     // B

    // ---- encoder: 512 dependent steps, both directions per launch ----
    for (int t=0;t<S;t++){
        enc_step_kernel<<<dim3(64,2), 256, 0, stream>>>(t, input_seq, emb,
            efWih, efWhh, efbih, efbhh, ebWih, ebWhh, ebbih, ebbhh, enc_out, outb);
    }
    prep_kernel<<<64, 256, 0, stream>>>(enc_out, outb, hdec, tok, lossb);
    combine_kernel<<<(B*(size_t)S*H/4)/256, 256, 0, stream>>>(enc_out, outb);

    // ---- decoder: 128 dependent steps ----
    for (int t=0;t<T;t++){
        float* hin  = hdec + (size_t)(t&1)*B*H;
        float* hout = hdec + (size_t)((t+1)&1)*B*H;
        dec_gru_kernel<<<64, 256, 0, stream>>>(tok, emb, dWih, dWhh, dbih, dbhh, hin, hout, cat);
        scores_kernel<<<dim3(B,8), 256, 0, stream>>>(hout, enc_out, scores);
        ctx_kernel<<<dim3(B,4), 256, 0, stream>>>(scores, enc_out, cat);
        proj_kernel<<<32, 256, 0, stream>>>(cat, attW, attb, attout);
        logits_kernel<<<LCHUNK, 256, 0, stream>>>(attout, outW, outBias, pm, ps, pidx);
        merge_kernel<<<B, 256, 0, stream>>>(t, target_seq, attout, outW, outBias, pm, ps, pidx, lossb, tok);
    }
    finalize_kernel<<<1, 64, 0, stream>>>(lossb, (float*)d_out);
}